// Round 5
// baseline (180.971 us; speedup 1.0000x reference)
//
#include <hip/hip_runtime.h>

typedef unsigned short u16;
typedef unsigned int u32;
typedef __bf16 bf16x8 __attribute__((ext_vector_type(8)));
typedef float f32x4 __attribute__((ext_vector_type(4)));

#define DEV __device__ __forceinline__

// Problem constants (B,T,D_MODEL,H) = (2,2048,1024,16)
constexpr int BB = 2;
constexpr int TT = 2048;
constexpr int CD = 1024;
constexpr int HH = 16;
constexpr int DH = 64;
constexpr int BT = BB * TT;   // 4096

// softmax scale 1/8 folded with log2(e): S' = S/8*log2e, exp(x)=exp2(x')
#define QSCALE 0.18033688011112042f

// Native bf16 convert (RTNE): compiler packs pairs into v_cvt_pk_bf16_f32.
DEV u16 f2bf(float f) {
    return __builtin_bit_cast(u16, (__bf16)f);
}

DEV f32x4 mfma16(bf16x8 a, bf16x8 b, f32x4 c) {
    return __builtin_amdgcn_mfma_f32_16x16x32_bf16(a, b, c, 0, 0, 0);
}

// Async global->LDS, 16B per lane: LDS dest = wave-uniform base + lane*16.
DEV void gld_lds16(u16* lds, const u16* g) {
    __builtin_amdgcn_global_load_lds(
        (const __attribute__((address_space(1))) unsigned int*)g,
        (__attribute__((address_space(3))) unsigned int*)lds, 16, 0, 0);
}

// ---------------------------------------------------------------------------
// Fused preprocessing (single launch):
//   blocks [0,2048):      x fp32 -> bf16           (4096x1024)
//   blocks [2048,5120):   W_qkv (1024x3072) -> transposed bf16 (3072x1024)
//   blocks [5120,6144):   W_o   (1024x1024) -> transposed bf16 (1024x1024)
// ---------------------------------------------------------------------------
__global__ __launch_bounds__(256)
void prep_kernel(const float* __restrict__ x, u16* __restrict__ xb,
                 const float* __restrict__ Wqkv, u16* __restrict__ WqkvT,
                 const float* __restrict__ Wo, u16* __restrict__ WoT) {
    const int tid = threadIdx.x;
    int blk = blockIdx.x;
    if (blk < 2048) {                       // convert job
        const int i = (blk * 256 + tid) * 8;
        float4 a = *(const float4*)&x[i];
        float4 b = *(const float4*)&x[i + 4];
        u16 t[8];
        t[0] = f2bf(a.x); t[1] = f2bf(a.y); t[2] = f2bf(a.z); t[3] = f2bf(a.w);
        t[4] = f2bf(b.x); t[5] = f2bf(b.y); t[6] = f2bf(b.z); t[7] = f2bf(b.w);
        *(uint4*)&xb[i] = *(const uint4*)t;
        return;                             // whole block exits (no barrier)
    }
    __shared__ u16 tile[32][33];
    const float* in; u16* out; int rows, cols, bx, by;
    if (blk < 5120) { blk -= 2048; in = Wqkv; out = WqkvT; rows = 1024; cols = 3072; bx = blk % 96; by = blk / 96; }
    else            { blk -= 5120; in = Wo;   out = WoT;   rows = 1024; cols = 1024; bx = blk % 32; by = blk / 32; }
    const int c0 = bx * 32, r0 = by * 32;
    const int tx = tid & 31, ty = tid >> 5;
    #pragma unroll
    for (int i = ty; i < 32; i += 8)
        tile[i][tx] = f2bf(in[(r0 + i) * cols + (c0 + tx)]);
    __syncthreads();
    #pragma unroll
    for (int i = ty; i < 32; i += 8)
        out[(c0 + i) * rows + (r0 + tx)] = tile[tx][i];
}

// ---------------------------------------------------------------------------
// GEMM v3: 3-deep pipelined staging + counted vmcnt (T4) + chunk-XOR LDS
// swizzle (T2).  C[M][N] = A[M][K] * Bt[N][K]^T, bf16->fp32 acc.
// BM=128, BN template (128 or 64), BK=32.  (Unchanged from round 4:
// conflicts measured 0; timing at the 2-phase-class structural plateau.)
// ---------------------------------------------------------------------------
template <int EPI, int BN, int GX>
__global__ __launch_bounds__(256)
void gemm_db(const u16* __restrict__ A, const u16* __restrict__ Bt,
             u16* __restrict__ out0, u16* __restrict__ out1,
             u16* __restrict__ out2, float* __restrict__ outf,
             int M, int N, int K) {
    constexpr int BM = 128, BK = 32, AST = 32;
    constexpr int NT = BN / 32;             // n-tiles per wave
    constexpr int NBLK = GX * 32;           // M/BM = 32 always here
    constexpr int CPX = NBLK / 8;           // blocks per XCD chunk
    __shared__ alignas(16) u16 As[3][BM * AST];
    __shared__ alignas(16) u16 Bs[3][BN * AST];

    const int tid  = threadIdx.x;
    const int wave = tid >> 6, lane = tid & 63;
    const int quad = lane >> 4, l16 = lane & 15;
    const int wm = (wave & 1) * 64, wn = (wave >> 1) * (BN / 2);

    // T1: XCD-aware chunked swizzle (bijective since NBLK % 8 == 0)
    int bid = (int)blockIdx.x;
    bid = (bid & 7) * CPX + (bid >> 3);
    const int bx = bid % GX, by = bid / GX;
    const int m0 = by * BM, n0 = bx * BN;

    // DMA staging: one instr = 64 lanes x 16B = 16 rows x 64B.
    // T2 pre-swizzled global source chunk.
    const int srowA = wave * 32 + (lane >> 2);
    const int srowB = wave * (BN / 4) + (lane >> 2);
    const int scol  = (((lane & 3) ^ ((lane >> 3) & 3))) * 8;
    const u16* ga0 = A  + (size_t)(m0 + srowA) * K + scol;
    const u16* ga1 = ga0 + (size_t)16 * K;
    const u16* gb0 = Bt + (size_t)(n0 + srowB) * K + scol;
    const u16* gb1 = gb0 + (size_t)16 * K;

    auto stage = [&](int buf, int k0) {
        gld_lds16(&As[buf][wave * 1024],           ga0 + k0);
        gld_lds16(&As[buf][wave * 1024 + 512],     ga1 + k0);
        gld_lds16(&Bs[buf][wave * (BN * 8)],       gb0 + k0);
        if constexpr (BN == 128)
            gld_lds16(&Bs[buf][wave * (BN * 8) + 512], gb1 + k0);
    };
    // mid-loop counted wait: one stage (LPS loads) stays in flight
    auto wait_lps = [&]() {
        if constexpr (BN == 128) asm volatile("s_waitcnt vmcnt(4)" ::: "memory");
        else                     asm volatile("s_waitcnt vmcnt(3)" ::: "memory");
    };

    f32x4 acc[4][NT] = {};

    stage(0, 0);
    stage(1, BK);
    wait_lps();                              // step-0 buffers landed
    __builtin_amdgcn_s_barrier();

    const int sx = ((l16 >> 1) & 3) * 8;     // T2 read-side XOR term
    const int NS = K / BK;
    int cb = 0;                              // current buffer
    for (int t = 0; t < NS; ++t) {
        const bool pf = (t + 2 < NS);
        int sb = cb + 2; if (sb >= 3) sb -= 3;
        if (pf) stage(sb, (t + 2) * BK);

        bf16x8 fa[4], fb[NT];
        #pragma unroll
        for (int mt = 0; mt < 4; ++mt)
            fa[mt] = *(const bf16x8*)
                &As[cb][(wm + mt * 16 + l16) * AST + (quad * 8 ^ sx)];
        #pragma unroll
        for (int nt = 0; nt < NT; ++nt)
            fb[nt] = *(const bf16x8*)
                &Bs[cb][(wn + nt * 16 + l16) * AST + (quad * 8 ^ sx)];
        #pragma unroll
        for (int mt = 0; mt < 4; ++mt)
            #pragma unroll
            for (int nt = 0; nt < NT; ++nt)
                acc[mt][nt] = mfma16(fa[mt], fb[nt], acc[mt][nt]);

        if (pf) wait_lps();                  // drain stage for step t+1 only
        else    asm volatile("s_waitcnt vmcnt(0)" ::: "memory");
        __builtin_amdgcn_s_barrier();
        cb = (cb + 1 == 3) ? 0 : cb + 1;
    }

    // Epilogue. C/D layout: row = quad*4+reg, col = l16.
    #pragma unroll
    for (int mt = 0; mt < 4; ++mt) {
        #pragma unroll
        for (int nt = 0; nt < NT; ++nt) {
            #pragma unroll
            for (int reg = 0; reg < 4; ++reg) {
                const int r = m0 + wm + mt * 16 + quad * 4 + reg;
                const int c = n0 + wn + nt * 16 + l16;
                if (EPI == 0) {
                    outf[(size_t)r * N + c] = acc[mt][nt][reg];
                } else {
                    const int which = c >> 10;       // 0=q 1=k 2=v
                    const int cc = c & 1023;
                    const int h = cc >> 6, d = cc & 63;
                    const int b = r >> 11, t = r & 2047;
                    const int bh = b * HH + h;
                    if (which == 0) {
                        out0[((size_t)bh * TT + t) * DH + d] =
                            f2bf(acc[mt][nt][reg] * QSCALE);
                    } else if (which == 1) {
                        out1[((size_t)bh * TT + t) * DH + d] = f2bf(acc[mt][nt][reg]);
                    } else {
                        out2[((size_t)bh * DH + d) * TT + t] = f2bf(acc[mt][nt][reg]);
                    }
                }
            }
        }
    }
}

// ---------------------------------------------------------------------------
// Flash attention v6 (causal): S^T formulation + paired-key full-K=32 PV.
// q-tile 128 per block; each wave owns TWO 16-row halves (rows w*16 and
// 64+w*16) -> K/V fragments read ONCE feed 32 MFMA/step/wave (32 FLOP/B,
// 2x v5's arithmetic intensity), chunk-load traffic halved, and the two
// halves' serial softmax chains are independent (ILP).  A-half skips its
// final fully-masked chunk.  Grid 512 = 2 blocks/CU; complement pairing:
// blocks [0,256) carry q=15..8, [256,512) q=7..0, so each CU's two blocks
// sum to a constant 34 steps; bh = bid&31 keeps bh%8 == XCD (L2 locality).
// K/V double-buffered in LDS; next chunk prefetched to registers.
// ---------------------------------------------------------------------------
constexpr int KST = 72;  // K/V LDS row stride (144 B, rows 16B-aligned)

// Softmax for one 16-row half: mask (if diag), row max/sum trees + 2 cross-
// quad shuffles, exp2-domain update, O-rescale.  qg = wave*16 + l16.
DEV void softmax_half(f32x4* st, f32x4* Oacc, float& m_i, float& l_i,
                      bool diag, int quad, int qg) {
    if (diag) {
        #pragma unroll
        for (int nt = 0; nt < 4; ++nt)
            #pragma unroll
            for (int reg = 0; reg < 4; ++reg) {
                const int kg = nt * 16 + quad * 4 + reg;
                st[nt][reg] = (kg <= qg) ? st[nt][reg] : -INFINITY;
            }
    }
    float v[16];
    #pragma unroll
    for (int nt = 0; nt < 4; ++nt)
        #pragma unroll
        for (int reg = 0; reg < 4; ++reg)
            v[nt * 4 + reg] = st[nt][reg];
    #pragma unroll
    for (int s = 8; s > 0; s >>= 1)
        #pragma unroll
        for (int i = 0; i < s; ++i)
            v[i] = fmaxf(v[i], v[i + s]);
    float vmax = v[0];
    vmax = fmaxf(vmax, __shfl_xor(vmax, 16, 64));
    vmax = fmaxf(vmax, __shfl_xor(vmax, 32, 64));

    const float mnew = fmaxf(m_i, vmax);
    const float alpha = __builtin_amdgcn_exp2f(m_i - mnew);
    m_i = mnew;

    #pragma unroll
    for (int nt = 0; nt < 4; ++nt)
        #pragma unroll
        for (int reg = 0; reg < 4; ++reg) {
            const float p = __builtin_amdgcn_exp2f(st[nt][reg] - mnew);
            st[nt][reg] = p;
            v[nt * 4 + reg] = p;
        }
    #pragma unroll
    for (int s = 8; s > 0; s >>= 1)
        #pragma unroll
        for (int i = 0; i < s; ++i)
            v[i] += v[i + s];
    float vsum = v[0];
    vsum += __shfl_xor(vsum, 16, 64);
    vsum += __shfl_xor(vsum, 32, 64);
    l_i = l_i * alpha + vsum;

    #pragma unroll
    for (int dt = 0; dt < 4; ++dt)
        #pragma unroll
        for (int reg = 0; reg < 4; ++reg)
            Oacc[dt][reg] *= alpha;
}

__global__ __launch_bounds__(256, 2)
void attn_kernel(const u16* __restrict__ Q, const u16* __restrict__ Kb,
                 const u16* __restrict__ Vt, u16* __restrict__ O) {
    __shared__ alignas(16) u16 Ks[2][64 * KST];
    __shared__ alignas(16) u16 Vs[2][64 * KST];

    // Complement pairing + XCD locality (see header).
    const int bid = (int)blockIdx.x;
    const int bh = bid & 31;
    const int q  = (bid < 256) ? 15 - (bid >> 5) : (bid >> 5) - 8;
    const int jA = 2 * q;          // diagonal chunk for half A
    const int jB = 2 * q + 1;      // diagonal chunk for half B (= jmax)

    const int tid = threadIdx.x;
    const int wave = tid >> 6, lane = tid & 63;
    const int quad = lane >> 4, l16 = lane & 15;

    const u16* Qh = Q  + (size_t)bh * TT * DH;
    const u16* Kh = Kb + (size_t)bh * TT * DH;
    const u16* Vh = Vt + (size_t)bh * DH * TT;

    const int rowA = q * 128 + wave * 16;
    const int rowB = q * 128 + 64 + wave * 16;

    // Q fragments (B-operand: n = l16 = q-row, k = quad*8+j over d)
    bf16x8 fqA[2], fqB[2];
    fqA[0] = *(const bf16x8*)&Qh[(rowA + l16) * DH + quad * 8];
    fqA[1] = *(const bf16x8*)&Qh[(rowA + l16) * DH + 32 + quad * 8];
    fqB[0] = *(const bf16x8*)&Qh[(rowB + l16) * DH + quad * 8];
    fqB[1] = *(const bf16x8*)&Qh[(rowB + l16) * DH + 32 + quad * 8];

    f32x4 OaA[4] = {}, OaB[4] = {};
    float mA = -INFINITY, lA = 0.f, mB = -INFINITY, lB = 0.f;

    // Chunk staging: thread i covers 16B at row (i>>3), col (i&7)*8, +row32.
    const int trow = tid >> 3;
    const int ic   = tid & 7;            // 8-key group index
    const int tcol = ic * 8;
    // V pair-permuted destination column for this thread's 8 keys:
    //   keys 8*ic..8*ic+7 -> cols c1..c1+3 and c1+8..c1+11
    const int vc1 = 32 * (ic >> 2) + 16 * (ic & 1) + 4 * ((ic & 3) >> 1);
    uint4 kr0, kr1, vr0, vr1;

    auto load_chunk = [&](int j) {
        const u16* ks = Kh + (size_t)j * 64 * DH;
        kr0 = *(const uint4*)&ks[trow * DH + tcol];
        kr1 = *(const uint4*)&ks[(trow + 32) * DH + tcol];
        const u16* vs = Vh + (size_t)j * 64;
        vr0 = *(const uint4*)&vs[(size_t)trow * TT + tcol];
        vr1 = *(const uint4*)&vs[(size_t)(trow + 32) * TT + tcol];
    };
    auto write_chunk = [&](int buf) {
        *(uint4*)&Ks[buf][trow * KST + tcol]        = kr0;
        *(uint4*)&Ks[buf][(trow + 32) * KST + tcol] = kr1;
        // V: split each 16B into two 8B halves at permuted columns
        *(uint2*)&Vs[buf][trow * KST + vc1]            = *(const uint2*)&vr0;
        *(uint2*)&Vs[buf][trow * KST + vc1 + 8]        = *((const uint2*)&vr0 + 1);
        *(uint2*)&Vs[buf][(trow + 32) * KST + vc1]     = *(const uint2*)&vr1;
        *(uint2*)&Vs[buf][(trow + 32) * KST + vc1 + 8] = *((const uint2*)&vr1 + 1);
    };

    load_chunk(0);
    write_chunk(0);

    for (int j = 0; j <= jB; ++j) {
        const int cur = j & 1;
        __syncthreads();                    // buf[cur] staged & visible
        if (j < jB) load_chunk(j + 1);      // loads fly during compute

        const bool doA = (j <= jA);
        const u16* Kc = Ks[cur];
        const u16* Vc = Vs[cur];

        // S^T for both halves: K fragments read ONCE, feed 2 q-halves.
        f32x4 sA[4], sB[4];
        #pragma unroll
        for (int nt = 0; nt < 4; ++nt) {
            const bf16x8 k0 = *(const bf16x8*)&Kc[(nt * 16 + l16) * KST + quad * 8];
            const bf16x8 k1 = *(const bf16x8*)&Kc[(nt * 16 + l16) * KST + 32 + quad * 8];
            if (doA) {
                f32x4 t = {};
                t = mfma16(k0, fqA[0], t);
                t = mfma16(k1, fqA[1], t);
                sA[nt] = t;
            }
            f32x4 u = {};
            u = mfma16(k0, fqB[0], u);
            u = mfma16(k1, fqB[1], u);
            sB[nt] = u;
        }

        // Independent softmax chains (ILP across the serial dependency).
        if (doA) softmax_half(sA, OaA, mA, lA, (j == jA), quad, wave * 16 + l16);
        softmax_half(sB, OaB, mB, lB, (j == jB), quad, wave * 16 + l16);

        // PV: V fragments read ONCE, feed both halves.
        // P^T B-operand: reg j<4 = s[2p][j] (key p*32+quad*4+j),
        //                reg j>=4 = s[2p+1][j-4] (key p*32+16+quad*4+j-4)
        #pragma unroll
        for (int pair = 0; pair < 2; ++pair) {
            bf16x8 pbA, pbB;
            #pragma unroll
            for (int jj = 0; jj < 4; ++jj) {
                pbA[jj]     = (__bf16)sA[2 * pair][jj];
                pbA[4 + jj] = (__bf16)sA[2 * pair + 1][jj];
                pbB[jj]     = (__bf16)sB[2 * pair][jj];
                pbB[4 + jj] = (__bf16)sB[2 * pair + 1][jj];
            }
            #pragma unroll
            for (int dt = 0; dt < 4; ++dt) {
                const bf16x8 fvd = *(const bf16x8*)
                    &Vc[(dt * 16 + l16) * KST + pair * 32 + quad * 8];
                if (doA) OaA[dt] = mfma16(fvd, pbA, OaA[dt]);
                OaB[dt] = mfma16(fvd, pbB, OaB[dt]);
            }
        }

        if (j < jB) write_chunk(cur ^ 1);   // after all buf[cur^1] readers done
    }

    // Epilogue: O^T rows d = dt*16+quad*4+reg, col q-row = l16; write (B,T,C).
    const int b = bh >> 4, h = bh & 15;
    const float rA = 1.f / lA, rB = 1.f / lB;
    #pragma unroll
    for (int dt = 0; dt < 4; ++dt) {
        u16 oa[4], ob[4];
        #pragma unroll
        for (int reg = 0; reg < 4; ++reg) {
            oa[reg] = f2bf(OaA[dt][reg] * rA);
            ob[reg] = f2bf(OaB[dt][reg] * rB);
        }
        *(uint2*)&O[((size_t)(b * TT + rowA + l16)) * CD + h * DH + dt * 16 + quad * 4] =
            *(const uint2*)oa;
        *(uint2*)&O[((size_t)(b * TT + rowB + l16)) * CD + h * DH + dt * 16 + quad * 4] =
            *(const uint2*)ob;
    }
}

// ---------------------------------------------------------------------------
extern "C" void kernel_launch(void* const* d_in, const int* in_sizes, int n_in,
                              void* d_out, int out_size, void* d_ws, size_t ws_size,
                              hipStream_t stream) {
    (void)in_sizes; (void)n_in; (void)out_size; (void)ws_size;
    const float* x    = (const float*)d_in[0];   // (4096, 1024) fp32
    const float* Wqkv = (const float*)d_in[1];   // (1024, 3072) fp32
    const float* Wo   = (const float*)d_in[2];   // (1024, 1024) fp32
    float* out = (float*)d_out;                  // (4096, 1024) fp32

    char* ws = (char*)d_ws;
    u16* xb    = (u16*)(ws + 0);                    // 4096x1024  (8 MB)
    u16* WqkvT = (u16*)(ws + (8u  << 20));          // 3072x1024  (6 MB)
    u16* WoT   = (u16*)(ws + (14u << 20));          // 1024x1024  (2 MB)
    u16* Qb    = (u16*)(ws + (16u << 20));          // (B,H,T,64) (8 MB)
    u16* Kb    = (u16*)(ws + (24u << 20));          // (B,H,T,64) (8 MB)
    u16* Vt    = (u16*)(ws + (32u << 20));          // (B,H,64,T) (8 MB)
    u16* attn  = (u16*)(ws + (40u << 20));          // (B,T,C)    (8 MB)

    prep_kernel<<<6144, 256, 0, stream>>>(x, xb, Wqkv, WqkvT, Wo, WoT);

    // qkv = x @ W_qkv (3-deep pipelined, 128x128): grid 768 = 3 blocks/CU.
    gemm_db<1, 128, 24><<<768, 256, 0, stream>>>(
        xb, WqkvT, Qb, Kb, Vt, nullptr, BT, 3072, CD);

    // attn: 512 blocks (q-tile 128, 2 halves/wave), complement-paired.
    attn_kernel<<<512, 256, 0, stream>>>(Qb, Kb, Vt, attn);

    // out = attn @ W_o (3-deep pipelined, 128x64): grid 512 = 2 blocks/CU.
    gemm_db<0, 64, 16><<<512, 256, 0, stream>>>(
        attn, WoT, nullptr, nullptr, nullptr, out, BT, CD, CD);
}